// Round 1
// baseline (328.861 us; speedup 1.0000x reference)
//
#include <hip/hip_runtime.h>

#define NNODE  50000
#define NHEDGE 10000
#define NEDGE  300000
#define HD     256

__device__ __forceinline__ float prelu(float v, float a){ return v > 0.f ? v : a * v; }

// ---------------------------------------------------------------------------
// Transpose W_n2e -> Wn2eT and W_e2n -> WeT  (tiny, once per call)
// ---------------------------------------------------------------------------
__global__ void k_transpose(const float* __restrict__ W_n2e, const float* __restrict__ W_e2n,
                            float* __restrict__ Wn2eT, float* __restrict__ WeT){
  int i = blockIdx.x;   // column of original
  int o = threadIdx.x;  // row of original
  Wn2eT[i*HD + o] = W_n2e[o*HD + i];
  WeT[i*HD + o]   = W_e2n[o*HD + i];
}

// ---------------------------------------------------------------------------
// WcT[i,o] = sum_h W_n2e[o,h]*W_in[h,i]  (combined input2hidden + n2e weight)
// block HD computes bc[o] = sum_h W_n2e[o,h]*b_in[h] + b_n2e[o]
// ---------------------------------------------------------------------------
__global__ void k_combine(const float* __restrict__ Wn2eT, const float* __restrict__ W_in,
                          const float* __restrict__ b_in, const float* __restrict__ b_n2e,
                          float* __restrict__ WcT, float* __restrict__ bc){
  int o = threadIdx.x;
  int i = blockIdx.x;
  if(i == HD){
    float acc = 0.f;
    for(int h = 0; h < HD; ++h) acc += Wn2eT[h*HD + o] * b_in[h];
    bc[o] = acc + b_n2e[o];
    return;
  }
  float acc = 0.f;
  for(int h = 0; h < HD; ++h) acc += Wn2eT[h*HD + o] * W_in[h*HD + i];
  WcT[i*HD + o] = acc;
}

// ---------------------------------------------------------------------------
// Histogram of segment sizes (both directions)
// ---------------------------------------------------------------------------
__global__ void k_hist(const int* __restrict__ node_idx, const int* __restrict__ hedge_idx,
                       int* __restrict__ he_cnt, int* __restrict__ node_cnt){
  int e = blockIdx.x*256 + threadIdx.x;
  if(e < NEDGE){
    atomicAdd(&he_cnt[hedge_idx[e]], 1);
    atomicAdd(&node_cnt[node_idx[e]], 1);
  }
}

// ---------------------------------------------------------------------------
// Exclusive scan, one block per array (block 0: hedges, block 1: nodes)
// ---------------------------------------------------------------------------
__global__ __launch_bounds__(1024) void k_scan(const int* __restrict__ he_cnt, int* __restrict__ he_off,
                                               const int* __restrict__ node_cnt, int* __restrict__ node_off){
  const int* in; int* out; int n;
  if(blockIdx.x == 0){ in = he_cnt;  out = he_off;  n = NHEDGE; }
  else               { in = node_cnt; out = node_off; n = NNODE; }
  __shared__ int part[1024];
  int t = threadIdx.x;
  int C = (n + 1023) >> 10;
  int lo = t*C, hi = lo + C; if(hi > n) hi = n; if(lo > n) lo = n;
  int s = 0;
  for(int i = lo; i < hi; ++i) s += in[i];
  part[t] = s;
  __syncthreads();
  for(int d = 1; d < 1024; d <<= 1){
    int v = (t >= d) ? part[t-d] : 0;
    __syncthreads();
    part[t] += v;
    __syncthreads();
  }
  int base = (t == 0) ? 0 : part[t-1];
  for(int i = lo; i < hi; ++i){ out[i] = base; base += in[i]; }
  if(t == 1023) out[n] = part[1023];
}

// ---------------------------------------------------------------------------
// Fill CSR buckets; store pre-resolved source row + weight (short dep chains
// in the hot aggregation loops).
// ---------------------------------------------------------------------------
__global__ void k_fill(const int* __restrict__ node_idx, const int* __restrict__ hedge_idx,
                       const float* __restrict__ nrw,
                       const int* __restrict__ he_off, int* __restrict__ he_pos,
                       int* __restrict__ he_src, float* __restrict__ he_w,
                       const int* __restrict__ node_off, int* __restrict__ node_pos,
                       int* __restrict__ node_src){
  int e = blockIdx.x*256 + threadIdx.x;
  if(e < NEDGE){
    int j = hedge_idx[e];
    int n = node_idx[e];
    int p = he_off[j] + atomicAdd(&he_pos[j], 1);
    he_src[p] = n;
    he_w[p]   = nrw[n];
    int q = node_off[n] + atomicAdd(&node_pos[n], 1);
    node_src[q] = j;
  }
}

// ---------------------------------------------------------------------------
// Phase-1 aggregation: agg_x[j] = sum_e w_e * n_feat[src_e], aggw[j] = sum w_e
// One wave per hedge, lane covers 4 columns (float4). 1-deep value prefetch.
// ---------------------------------------------------------------------------
__global__ __launch_bounds__(256) void k_agg1(const float* __restrict__ n_feat,
                                              const int* __restrict__ he_off,
                                              const int* __restrict__ he_src,
                                              const float* __restrict__ he_w,
                                              float* __restrict__ aggx, float* __restrict__ aggw){
  int wave = threadIdx.x >> 6;
  int lane = threadIdx.x & 63;
  int j = blockIdx.x*4 + wave;
  if(j >= NHEDGE) return;
  int b   = he_off[j];
  int cnt = he_off[j+1] - b;
  const float4* nf4 = (const float4*)n_feat;
  float4 acc = make_float4(0.f, 0.f, 0.f, 0.f);
  float  sw  = 0.f;
  float4 v = make_float4(0.f, 0.f, 0.f, 0.f);
  float  w = 0.f;
  if(cnt > 0){ int n = he_src[b]; w = he_w[b]; v = nf4[(size_t)n*64 + lane]; }
  for(int k = 0; k < cnt; ++k){
    float4 cv = v; float cw = w;
    if(k + 1 < cnt){ int n = he_src[b+k+1]; w = he_w[b+k+1]; v = nf4[(size_t)n*64 + lane]; }
    acc.x += cw*cv.x; acc.y += cw*cv.y; acc.z += cw*cv.z; acc.w += cw*cv.w;
    sw += cw;
  }
  ((float4*)aggx)[(size_t)j*64 + lane] = acc;
  if(lane == 0) aggw[j] = sw;
}

// ---------------------------------------------------------------------------
// 64x64-tile f32 GEMM over [M,256] x WT[256,256], with fused epilogue.
// MODE 0: out = prelu((dot + rs_a[r]*cb[o]) / rs_b[r])      (efeat)
// MODE 1: out = rs_a[r] * (dot + cb[o])                      (y)
// ---------------------------------------------------------------------------
template<int MODE>
__global__ __launch_bounds__(256) void k_gemm(const float* __restrict__ x, const float* __restrict__ WT,
                                              float* __restrict__ out,
                                              const float* __restrict__ rs_a,
                                              const float* __restrict__ rs_b,
                                              const float* __restrict__ cb,
                                              const float* __restrict__ alpha_p, int M){
  __shared__ float xs[16][64];  // [k][row]
  __shared__ float ws[16][64];  // [k][col]
  int tid = threadIdx.x;
  int bm = blockIdx.x, bn = blockIdx.y;
  int tn = tid & 15, tm = tid >> 4;
  int xrow = tid >> 2, xk4 = (tid & 3) << 2;
  int wk = tid >> 4,  wc4 = (tid & 15) << 2;
  int grow = bm*64 + xrow;
  float a4[4][4] = {};
  for(int kc = 0; kc < HD; kc += 16){
    float4 xv = make_float4(0.f,0.f,0.f,0.f);
    if(grow < M) xv = *(const float4*)&x[(size_t)grow*HD + kc + xk4];
    float4 wv = *(const float4*)&WT[(size_t)(kc + wk)*HD + bn*64 + wc4];
    __syncthreads();
    xs[xk4+0][xrow] = xv.x; xs[xk4+1][xrow] = xv.y;
    xs[xk4+2][xrow] = xv.z; xs[xk4+3][xrow] = xv.w;
    *(float4*)&ws[wk][wc4] = wv;
    __syncthreads();
    #pragma unroll
    for(int k = 0; k < 16; ++k){
      float4 av = *(const float4*)&xs[k][tm << 2];
      float4 bv = *(const float4*)&ws[k][tn << 2];
      a4[0][0] += av.x*bv.x; a4[0][1] += av.x*bv.y; a4[0][2] += av.x*bv.z; a4[0][3] += av.x*bv.w;
      a4[1][0] += av.y*bv.x; a4[1][1] += av.y*bv.y; a4[1][2] += av.y*bv.z; a4[1][3] += av.y*bv.w;
      a4[2][0] += av.z*bv.x; a4[2][1] += av.z*bv.y; a4[2][2] += av.z*bv.z; a4[2][3] += av.z*bv.w;
      a4[3][0] += av.w*bv.x; a4[3][1] += av.w*bv.y; a4[3][2] += av.w*bv.z; a4[3][3] += av.w*bv.w;
    }
  }
  float alpha = (MODE == 0) ? *alpha_p : 0.f;
  int c0 = bn*64 + (tn << 2);
  #pragma unroll
  for(int i = 0; i < 4; ++i){
    int r = bm*64 + (tm << 2) + i;
    if(r < M){
      float av = rs_a[r];
      float o0, o1, o2, o3;
      if(MODE == 0){
        float inv = 1.f / rs_b[r];
        o0 = prelu((a4[i][0] + av*cb[c0+0]) * inv, alpha);
        o1 = prelu((a4[i][1] + av*cb[c0+1]) * inv, alpha);
        o2 = prelu((a4[i][2] + av*cb[c0+2]) * inv, alpha);
        o3 = prelu((a4[i][3] + av*cb[c0+3]) * inv, alpha);
      } else {
        o0 = av * (a4[i][0] + cb[c0+0]);
        o1 = av * (a4[i][1] + cb[c0+1]);
        o2 = av * (a4[i][2] + cb[c0+2]);
        o3 = av * (a4[i][3] + cb[c0+3]);
      }
      *(float4*)&out[(size_t)r*HD + c0] = make_float4(o0, o1, o2, o3);
    }
  }
}

// ---------------------------------------------------------------------------
// Phase-2 aggregation + final epilogue:
// out_nodes[i] = prelu( (sum_e y[hedge_e]) / node_reg_sum[i] )
// ---------------------------------------------------------------------------
__global__ __launch_bounds__(256) void k_agg2(const float* __restrict__ y,
                                              const int* __restrict__ node_off,
                                              const int* __restrict__ node_src,
                                              const float* __restrict__ nrs,
                                              const float* __restrict__ alpha_p,
                                              float* __restrict__ out_nodes){
  int wave = threadIdx.x >> 6;
  int lane = threadIdx.x & 63;
  int i = blockIdx.x*4 + wave;
  if(i >= NNODE) return;
  int b   = node_off[i];
  int cnt = node_off[i+1] - b;
  const float4* y4 = (const float4*)y;
  float4 acc = make_float4(0.f, 0.f, 0.f, 0.f);
  float4 v = make_float4(0.f, 0.f, 0.f, 0.f);
  if(cnt > 0){ int jj = node_src[b]; v = y4[(size_t)jj*64 + lane]; }
  for(int k = 0; k < cnt; ++k){
    float4 cv = v;
    if(k + 1 < cnt){ int jj = node_src[b+k+1]; v = y4[(size_t)jj*64 + lane]; }
    acc.x += cv.x; acc.y += cv.y; acc.z += cv.z; acc.w += cv.w;
  }
  float inv = 1.f / nrs[i];
  float a = *alpha_p;
  float4 o;
  o.x = prelu(acc.x*inv, a); o.y = prelu(acc.y*inv, a);
  o.z = prelu(acc.z*inv, a); o.w = prelu(acc.w*inv, a);
  ((float4*)out_nodes)[(size_t)i*64 + lane] = o;
}

// ---------------------------------------------------------------------------
extern "C" void kernel_launch(void* const* d_in, const int* in_sizes, int n_in,
                              void* d_out, int out_size, void* d_ws, size_t ws_size,
                              hipStream_t stream){
  const float* n_feat   = (const float*)d_in[0];
  // d_in[1] he_feat: unused by the reference
  const int*   node_idx  = (const int*)d_in[2];
  const int*   hedge_idx = (const int*)d_in[3];
  const float* nrw  = (const float*)d_in[4];   // node_reg_weight
  const float* nrs  = (const float*)d_in[5];   // node_reg_sum
  const float* hrw  = (const float*)d_in[6];   // hedge_reg_weight
  const float* hrs  = (const float*)d_in[7];   // hedge_reg_sum
  const float* W_in  = (const float*)d_in[8];
  const float* b_in  = (const float*)d_in[9];
  const float* W_n2e = (const float*)d_in[10];
  const float* b_n2e = (const float*)d_in[11];
  const float* W_e2n = (const float*)d_in[12];
  const float* b_e2n = (const float*)d_in[13];
  const float* alpha = (const float*)d_in[14];

  float* out_nodes = (float*)d_out;
  float* out_efeat = out_nodes + (size_t)NNODE * HD;

  // workspace layout (~15.6 MB)
  char* p = (char*)d_ws;
  auto take = [&](size_t bytes) -> void* {
    void* r = (void*)p;
    p += (bytes + 255) & ~(size_t)255;
    return r;
  };
  float* WcT    = (float*)take((size_t)HD*HD*sizeof(float));
  float* WeT    = (float*)take((size_t)HD*HD*sizeof(float));
  float* Wn2eT  = (float*)take((size_t)HD*HD*sizeof(float));
  float* bc     = (float*)take(HD*sizeof(float));
  float* aggw   = (float*)take(NHEDGE*sizeof(float));
  float* aggx   = (float*)take((size_t)NHEDGE*HD*sizeof(float)); // later aliased as y
  int*   he_off   = (int*)take((NHEDGE+1)*sizeof(int));
  int*   node_off = (int*)take((NNODE+1)*sizeof(int));
  int*   counters = (int*)take((size_t)2*(NHEDGE+NNODE)*sizeof(int));
  int*   he_cnt   = counters;
  int*   he_pos   = counters + NHEDGE;
  int*   node_cnt = counters + 2*NHEDGE;
  int*   node_pos = node_cnt + NNODE;
  int*   he_src   = (int*)take(NEDGE*sizeof(int));
  float* he_w     = (float*)take(NEDGE*sizeof(float));
  int*   node_src = (int*)take(NEDGE*sizeof(int));
  float* ybuf = aggx;  // safe alias: aggx dead after k_gemm<0>

  hipMemsetAsync(counters, 0, (size_t)2*(NHEDGE+NNODE)*sizeof(int), stream);

  k_transpose<<<HD, HD, 0, stream>>>(W_n2e, W_e2n, Wn2eT, WeT);
  k_combine<<<HD+1, HD, 0, stream>>>(Wn2eT, W_in, b_in, b_n2e, WcT, bc);
  k_hist<<<(NEDGE+255)/256, 256, 0, stream>>>(node_idx, hedge_idx, he_cnt, node_cnt);
  k_scan<<<2, 1024, 0, stream>>>(he_cnt, he_off, node_cnt, node_off);
  k_fill<<<(NEDGE+255)/256, 256, 0, stream>>>(node_idx, hedge_idx, nrw,
                                              he_off, he_pos, he_src, he_w,
                                              node_off, node_pos, node_src);
  k_agg1<<<NHEDGE/4, 256, 0, stream>>>(n_feat, he_off, he_src, he_w, aggx, aggw);
  k_gemm<0><<<dim3((NHEDGE+63)/64, 4), 256, 0, stream>>>(aggx, WcT, out_efeat,
                                                         aggw, hrs, bc, alpha, NHEDGE);
  k_gemm<1><<<dim3((NHEDGE+63)/64, 4), 256, 0, stream>>>(out_efeat, WeT, ybuf,
                                                         hrw, nullptr, b_e2n, alpha, NHEDGE);
  k_agg2<<<NNODE/4, 256, 0, stream>>>(ybuf, node_off, node_src, nrs, alpha, out_nodes);
}

// Round 2
// 228.667 us; speedup vs baseline: 1.4382x; 1.4382x over previous
//
#include <hip/hip_runtime.h>

#define NNODE  50000
#define NHEDGE 10000
#define NEDGE  300000
#define HD     256
#define NS     (NHEDGE + NNODE)   // 60000 combined segments
#define SCAN_B 59                 // ceil(NS/1024)

typedef __attribute__((ext_vector_type(8))) short bf16x8;
typedef __attribute__((ext_vector_type(4))) float f32x4;

__device__ __forceinline__ float prelu(float v, float a){ return v > 0.f ? v : a*v; }
__device__ __forceinline__ unsigned short f2bf(float f){
  unsigned u = __float_as_uint(f);
  return (unsigned short)((u + 0x7FFFu + ((u>>16)&1u)) >> 16);   // RNE
}
__device__ __forceinline__ float bf2f(unsigned short h){
  return __uint_as_float(((unsigned)h) << 16);
}

// ---------------------------------------------------------------------------
// Weight prep: Wb0[o][i] = bf16( sum_h W_n2e[o][h]*W_in[h][i] )   (B for GEMM0, [n][k])
//              Wb1[o][i] = bf16( W_e2n[o][i] )                    (B for GEMM1, [n][k])
//              block HD: bc[o] = dot(W_n2e[o], b_in) + b_n2e[o]   (kept f32)
// ---------------------------------------------------------------------------
__global__ __launch_bounds__(256) void k_wprep(const float* __restrict__ W_in, const float* __restrict__ b_in,
        const float* __restrict__ W_n2e, const float* __restrict__ b_n2e,
        const float* __restrict__ W_e2n,
        unsigned short* __restrict__ Wb0, unsigned short* __restrict__ Wb1,
        float* __restrict__ bc){
  int o = blockIdx.x;
  int i = threadIdx.x;
  if(o == HD){
    float acc = 0.f;
    for(int h = 0; h < HD; ++h) acc += W_n2e[(size_t)i*HD + h] * b_in[h];
    bc[i] = acc + b_n2e[i];
    return;
  }
  __shared__ float wn[HD];
  wn[i] = W_n2e[(size_t)o*HD + i];
  __syncthreads();
  float acc = 0.f;
  #pragma unroll 8
  for(int h = 0; h < HD; ++h) acc += wn[h] * W_in[(size_t)h*HD + i];
  Wb0[(size_t)o*HD + i] = f2bf(acc);
  Wb1[(size_t)o*HD + i] = f2bf(W_e2n[(size_t)o*HD + i]);
}

// ---------------------------------------------------------------------------
// Combined histogram: cnts[0..NHEDGE) hedge sizes, cnts[NHEDGE..NS) node sizes
// ---------------------------------------------------------------------------
__global__ void k_hist(const int* __restrict__ node_idx, const int* __restrict__ hedge_idx,
                       int* __restrict__ cnts){
  int e = blockIdx.x*256 + threadIdx.x;
  if(e < NEDGE){
    atomicAdd(&cnts[hedge_idx[e]], 1);
    atomicAdd(&cnts[NHEDGE + node_idx[e]], 1);
  }
}

// ---------------------------------------------------------------------------
// Parallel exclusive scan over NS counts: A) block sums  B) scan partials  C) emit
// ---------------------------------------------------------------------------
__global__ __launch_bounds__(256) void k_scanA(const int* __restrict__ cnts, int* __restrict__ bsum){
  int idx4 = blockIdx.x*256 + threadIdx.x;
  int4 v = make_int4(0,0,0,0);
  if(idx4 < NS/4) v = ((const int4*)cnts)[idx4];
  int s = v.x + v.y + v.z + v.w;
  __shared__ int red[256];
  red[threadIdx.x] = s; __syncthreads();
  for(int d = 128; d > 0; d >>= 1){
    if(threadIdx.x < d) red[threadIdx.x] += red[threadIdx.x + d];
    __syncthreads();
  }
  if(threadIdx.x == 0) bsum[blockIdx.x] = red[0];
}

__global__ __launch_bounds__(64) void k_scanB(int* __restrict__ bsum){
  __shared__ int sb[SCAN_B];
  int t = threadIdx.x;
  if(t < SCAN_B) sb[t] = bsum[t];
  __syncthreads();
  if(t == 0){ int run = 0; for(int i = 0; i < SCAN_B; ++i){ int v = sb[i]; sb[i] = run; run += v; } }
  __syncthreads();
  if(t < SCAN_B) bsum[t] = sb[t];
}

__global__ __launch_bounds__(256) void k_scanC(const int* __restrict__ cnts, const int* __restrict__ bsum,
                                               int* __restrict__ offs){
  int t = threadIdx.x;
  int idx4 = blockIdx.x*256 + t;
  int4 v = make_int4(0,0,0,0);
  if(idx4 < NS/4) v = ((const int4*)cnts)[idx4];
  int s = v.x + v.y + v.z + v.w;
  __shared__ int sc[256];
  sc[t] = s; __syncthreads();
  for(int d = 1; d < 256; d <<= 1){
    int q = (t >= d) ? sc[t-d] : 0; __syncthreads();
    sc[t] += q; __syncthreads();
  }
  int excl = sc[t] - s + bsum[blockIdx.x];
  int base = idx4*4;
  if(base < NS){
    int r = excl;
    offs[base]   = r; r += v.x;
    offs[base+1] = r; r += v.y;
    offs[base+2] = r; r += v.z;
    offs[base+3] = r;
  }
  if(blockIdx.x == SCAN_B-1 && t == 255) offs[NS] = sc[255] + bsum[blockIdx.x];
}

// ---------------------------------------------------------------------------
// Fill CSR buckets (hedge buckets land in csrc[0..NEDGE), node buckets in
// csrc[NEDGE..2*NEDGE) automatically via the combined offsets).
// ---------------------------------------------------------------------------
__global__ void k_fill(const int* __restrict__ node_idx, const int* __restrict__ hedge_idx,
                       const float* __restrict__ nrw,
                       const int* __restrict__ offs, int* __restrict__ pos,
                       int* __restrict__ csrc, float* __restrict__ he_w){
  int e = blockIdx.x*256 + threadIdx.x;
  if(e < NEDGE){
    int j = hedge_idx[e];
    int n = node_idx[e];
    int p = offs[j] + atomicAdd(&pos[j], 1);
    csrc[p] = n;
    he_w[p] = nrw[n];
    int q = offs[NHEDGE + n] + atomicAdd(&pos[NHEDGE + n], 1);
    csrc[q] = j;
  }
}

// ---------------------------------------------------------------------------
// Phase-1 aggregation -> bf16 aggx + f32 aggw. One wave per hedge, lane = 4 cols.
// ---------------------------------------------------------------------------
__global__ __launch_bounds__(256) void k_agg1(const float* __restrict__ n_feat,
        const int* __restrict__ offs, const int* __restrict__ csrc, const float* __restrict__ he_w,
        unsigned short* __restrict__ aggx_b, float* __restrict__ aggw){
  int wv = threadIdx.x >> 6, lane = threadIdx.x & 63;
  int j = blockIdx.x*4 + wv;
  int b = offs[j], cnt = offs[j+1] - b;
  const float4* nf4 = (const float4*)n_feat;
  float4 acc = make_float4(0.f,0.f,0.f,0.f);
  float sw = 0.f;
  float4 v = make_float4(0.f,0.f,0.f,0.f);
  float w = 0.f;
  if(cnt > 0){ int n = csrc[b]; w = he_w[b]; v = nf4[(size_t)n*64 + lane]; }
  for(int k = 0; k < cnt; ++k){
    float4 cv = v; float cw = w;
    if(k + 1 < cnt){ int n = csrc[b+k+1]; w = he_w[b+k+1]; v = nf4[(size_t)n*64 + lane]; }
    acc.x += cw*cv.x; acc.y += cw*cv.y; acc.z += cw*cv.z; acc.w += cw*cv.w;
    sw += cw;
  }
  ushort4 ob;
  ob.x = f2bf(acc.x); ob.y = f2bf(acc.y); ob.z = f2bf(acc.z); ob.w = f2bf(acc.w);
  *(ushort4*)&aggx_b[(size_t)j*HD + lane*4] = ob;
  if(lane == 0) aggw[j] = sw;
}

// ---------------------------------------------------------------------------
// MFMA bf16 GEMM: per wave a 32x64 output tile (2 A-frag x 4 B-frag per K-step),
// operands straight from L2 (no LDS, no barriers). B is [n][k] row-major bf16.
// MODE 0: v = prelu((dot + rs_a[r]*cb[c]) / rs_b[r]) -> out_f (f32) + out_b (bf16)
// MODE 1: v = rs_a[r] * (dot + cb[c])               -> out_b (bf16)
// A-frag: lane&15 = row, k = 8*(lane>>4)+i ; B-frag: lane&15 = col, same k.
// C/D: col = lane&15, row = 4*(lane>>4)+reg  [verified layout]
// ---------------------------------------------------------------------------
template<int MODE>
__global__ __launch_bounds__(256) void k_gemm(const unsigned short* __restrict__ xb,
        const unsigned short* __restrict__ Wb,
        const float* __restrict__ rs_a, const float* __restrict__ rs_b,
        const float* __restrict__ cb, const float* __restrict__ alpha_p,
        float* __restrict__ out_f, unsigned short* __restrict__ out_b, int M){
  int wv = threadIdx.x >> 6, lane = threadIdx.x & 63;
  int m0 = blockIdx.x*128 + wv*32;
  int n0 = blockIdx.y*64;
  if(m0 >= M) return;
  int lr = lane & 15;
  int lk = (lane >> 4) << 3;
  f32x4 acc[2][4];
  #pragma unroll
  for(int a = 0; a < 2; ++a)
    #pragma unroll
    for(int b = 0; b < 4; ++b) acc[a][b] = (f32x4){0.f,0.f,0.f,0.f};
  const bf16x8 zero8 = {0,0,0,0,0,0,0,0};
  #pragma unroll
  for(int kc = 0; kc < HD; kc += 32){
    bf16x8 af[2], bf[4];
    #pragma unroll
    for(int mi = 0; mi < 2; ++mi){
      int r = m0 + mi*16 + lr;
      af[mi] = (r < M) ? *(const bf16x8*)&xb[(size_t)r*HD + kc + lk] : zero8;
    }
    #pragma unroll
    for(int ni = 0; ni < 4; ++ni){
      int c = n0 + ni*16 + lr;
      bf[ni] = *(const bf16x8*)&Wb[(size_t)c*HD + kc + lk];
    }
    #pragma unroll
    for(int mi = 0; mi < 2; ++mi)
      #pragma unroll
      for(int ni = 0; ni < 4; ++ni)
        acc[mi][ni] = __builtin_amdgcn_mfma_f32_16x16x32_bf16(af[mi], bf[ni], acc[mi][ni], 0, 0, 0);
  }
  float alpha = (MODE == 0) ? *alpha_p : 0.f;
  int rb = (lane >> 4) << 2;
  #pragma unroll
  for(int mi = 0; mi < 2; ++mi){
    #pragma unroll
    for(int j = 0; j < 4; ++j){
      int r = m0 + mi*16 + rb + j;
      if(r < M){
        float ra = rs_a[r];
        float inv = (MODE == 0) ? 1.f / rs_b[r] : 0.f;
        #pragma unroll
        for(int ni = 0; ni < 4; ++ni){
          int c = n0 + ni*16 + lr;
          float d = acc[mi][ni][j];
          if(MODE == 0){
            float v = (d + ra*cb[c]) * inv;
            v = prelu(v, alpha);
            out_f[(size_t)r*HD + c] = v;
            out_b[(size_t)r*HD + c] = f2bf(v);
          } else {
            float v = ra * (d + cb[c]);
            out_b[(size_t)r*HD + c] = f2bf(v);
          }
        }
      }
    }
  }
}

// ---------------------------------------------------------------------------
// Phase-2 aggregation from bf16 y + final epilogue. Lane = 4 cols (ushort4).
// ---------------------------------------------------------------------------
__global__ __launch_bounds__(256) void k_agg2(const unsigned short* __restrict__ yb,
        const int* __restrict__ offs, const int* __restrict__ csrc,
        const float* __restrict__ nrs, const float* __restrict__ alpha_p,
        float* __restrict__ out_nodes){
  int wv = threadIdx.x >> 6, lane = threadIdx.x & 63;
  int i = blockIdx.x*4 + wv;
  int b = offs[NHEDGE + i], cnt = offs[NHEDGE + i + 1] - b;
  float4 acc = make_float4(0.f,0.f,0.f,0.f);
  ushort4 v = {0,0,0,0};
  if(cnt > 0){ int j = csrc[b]; v = *(const ushort4*)&yb[(size_t)j*HD + lane*4]; }
  for(int k = 0; k < cnt; ++k){
    ushort4 cv = v;
    if(k + 1 < cnt){ int j = csrc[b+k+1]; v = *(const ushort4*)&yb[(size_t)j*HD + lane*4]; }
    acc.x += bf2f(cv.x); acc.y += bf2f(cv.y); acc.z += bf2f(cv.z); acc.w += bf2f(cv.w);
  }
  float inv = 1.f / nrs[i];
  float a = *alpha_p;
  float4 o;
  o.x = prelu(acc.x*inv, a); o.y = prelu(acc.y*inv, a);
  o.z = prelu(acc.z*inv, a); o.w = prelu(acc.w*inv, a);
  *(float4*)&out_nodes[(size_t)i*HD + lane*4] = o;
}

// ---------------------------------------------------------------------------
extern "C" void kernel_launch(void* const* d_in, const int* in_sizes, int n_in,
                              void* d_out, int out_size, void* d_ws, size_t ws_size,
                              hipStream_t stream){
  const float* n_feat   = (const float*)d_in[0];
  const int*   node_idx  = (const int*)d_in[2];
  const int*   hedge_idx = (const int*)d_in[3];
  const float* nrw  = (const float*)d_in[4];
  const float* nrs  = (const float*)d_in[5];
  const float* hrw  = (const float*)d_in[6];
  const float* hrs  = (const float*)d_in[7];
  const float* W_in  = (const float*)d_in[8];
  const float* b_in  = (const float*)d_in[9];
  const float* W_n2e = (const float*)d_in[10];
  const float* b_n2e = (const float*)d_in[11];
  const float* W_e2n = (const float*)d_in[12];
  const float* b_e2n = (const float*)d_in[13];
  const float* alpha = (const float*)d_in[14];

  float* out_nodes = (float*)d_out;
  float* out_efeat = out_nodes + (size_t)NNODE * HD;

  char* p = (char*)d_ws;
  auto take = [&](size_t bytes) -> void* {
    void* r = (void*)p;
    p += (bytes + 255) & ~(size_t)255;
    return r;
  };
  unsigned short* Wb0     = (unsigned short*)take((size_t)HD*HD*2);
  unsigned short* Wb1     = (unsigned short*)take((size_t)HD*HD*2);
  float*          bc      = (float*)take(HD*4);
  float*          aggw    = (float*)take(NHEDGE*4);
  unsigned short* aggx_b  = (unsigned short*)take((size_t)NHEDGE*HD*2);  // aliased as ybuf_b
  unsigned short* efeat_b = (unsigned short*)take((size_t)NHEDGE*HD*2);
  int*            offs    = (int*)take((NS+1)*4);
  int*            cntpos  = (int*)take((size_t)2*NS*4);   // cnts | pos (memset)
  int*            cnts    = cntpos;
  int*            pos     = cntpos + NS;
  int*            bsum    = (int*)take(SCAN_B*4);
  int*            csrc    = (int*)take((size_t)2*NEDGE*4);
  float*          he_w    = (float*)take((size_t)NEDGE*4);
  unsigned short* ybuf_b  = aggx_b;  // safe alias: aggx dead after k_gemm<0>

  hipMemsetAsync(cntpos, 0, (size_t)2*NS*4, stream);

  k_wprep<<<HD+1, 256, 0, stream>>>(W_in, b_in, W_n2e, b_n2e, W_e2n, Wb0, Wb1, bc);
  k_hist<<<(NEDGE+255)/256, 256, 0, stream>>>(node_idx, hedge_idx, cnts);
  k_scanA<<<SCAN_B, 256, 0, stream>>>(cnts, bsum);
  k_scanB<<<1, 64, 0, stream>>>(bsum);
  k_scanC<<<SCAN_B, 256, 0, stream>>>(cnts, bsum, offs);
  k_fill<<<(NEDGE+255)/256, 256, 0, stream>>>(node_idx, hedge_idx, nrw, offs, pos, csrc, he_w);
  k_agg1<<<NHEDGE/4, 256, 0, stream>>>(n_feat, offs, csrc, he_w, aggx_b, aggw);
  k_gemm<0><<<dim3((NHEDGE+127)/128, 4), 256, 0, stream>>>(aggx_b, Wb0, aggw, hrs, bc, alpha,
                                                           out_efeat, efeat_b, NHEDGE);
  k_gemm<1><<<dim3((NHEDGE+127)/128, 4), 256, 0, stream>>>(efeat_b, Wb1, hrw, nullptr, b_e2n, alpha,
                                                           nullptr, ybuf_b, NHEDGE);
  k_agg2<<<NNODE/4, 256, 0, stream>>>(ybuf_b, offs, csrc, nrs, alpha, out_nodes);
}

// Round 3
// 203.789 us; speedup vs baseline: 1.6137x; 1.1221x over previous
//
#include <hip/hip_runtime.h>

#define NNODE  50000
#define NHEDGE 10000
#define NEDGE  300000
#define HD     256
#define NS     (NHEDGE + NNODE)   // 60000 combined segments
#define SCAN_B 59                 // ceil(NS/1024)
#define HIST_B ((NEDGE + 255) / 256)            // 1172
#define CVT_B  ((NNODE * HD) / (256 * 8))       // 6250  (exact: 12.8M / 2048)

typedef __attribute__((ext_vector_type(8))) short bf16x8;
typedef __attribute__((ext_vector_type(8))) unsigned short u16x8;
typedef __attribute__((ext_vector_type(4))) float f32x4;

__device__ __forceinline__ float prelu(float v, float a){ return v > 0.f ? v : a*v; }
__device__ __forceinline__ unsigned short f2bf(float f){
  unsigned u = __float_as_uint(f);
  return (unsigned short)((u + 0x7FFFu + ((u>>16)&1u)) >> 16);   // RNE
}
__device__ __forceinline__ float bf2f(unsigned short h){
  return __uint_as_float(((unsigned)h) << 16);
}

// ---------------------------------------------------------------------------
// Merged prep kernel (independent work, branch on blockIdx):
//  blocks [0, HD]           : Wb0 = bf16(W_n2e @ W_in) row o ([n][k] for GEMM0),
//                             Wb1 = bf16(W_e2n) row o; block HD computes bc.
//  blocks [HD+1, +HIST_B)   : combined segment histogram.
//  blocks [.., +CVT_B)      : n_feat f32 -> bf16 table.
// ---------------------------------------------------------------------------
__global__ __launch_bounds__(256) void k_prep(
    const float* __restrict__ W_in, const float* __restrict__ b_in,
    const float* __restrict__ W_n2e, const float* __restrict__ b_n2e,
    const float* __restrict__ W_e2n,
    const int* __restrict__ node_idx, const int* __restrict__ hedge_idx,
    const float* __restrict__ n_feat,
    unsigned short* __restrict__ Wb0, unsigned short* __restrict__ Wb1,
    float* __restrict__ bc, int* __restrict__ cnts,
    unsigned short* __restrict__ nf_b){
  int blk = blockIdx.x;
  int t = threadIdx.x;
  if(blk <= HD){
    int o = blk;
    if(o == HD){
      float acc = 0.f;
      for(int h = 0; h < HD; ++h) acc += W_n2e[(size_t)t*HD + h] * b_in[h];
      bc[t] = acc + b_n2e[t];
      return;
    }
    __shared__ float wn[HD];
    wn[t] = W_n2e[(size_t)o*HD + t];
    __syncthreads();
    float acc = 0.f;
    #pragma unroll 8
    for(int h = 0; h < HD; ++h) acc += wn[h] * W_in[(size_t)h*HD + t];
    Wb0[(size_t)o*HD + t] = f2bf(acc);
    Wb1[(size_t)o*HD + t] = f2bf(W_e2n[(size_t)o*HD + t]);
  } else if(blk <= HD + HIST_B){
    int e = (blk - HD - 1)*256 + t;
    if(e < NEDGE){
      atomicAdd(&cnts[hedge_idx[e]], 1);
      atomicAdd(&cnts[NHEDGE + node_idx[e]], 1);
    }
  } else {
    size_t i8 = (size_t)(blk - HD - 1 - HIST_B)*256 + t;   // one thread = 8 elems
    const float4* f4 = (const float4*)n_feat;
    float4 a = f4[i8*2], c = f4[i8*2 + 1];
    u16x8 o;
    o[0] = f2bf(a.x); o[1] = f2bf(a.y); o[2] = f2bf(a.z); o[3] = f2bf(a.w);
    o[4] = f2bf(c.x); o[5] = f2bf(c.y); o[6] = f2bf(c.z); o[7] = f2bf(c.w);
    ((u16x8*)nf_b)[i8] = o;
  }
}

// ---------------------------------------------------------------------------
// Parallel exclusive scan over NS counts: A) block sums  B) scan partials  C) emit
// ---------------------------------------------------------------------------
__global__ __launch_bounds__(256) void k_scanA(const int* __restrict__ cnts, int* __restrict__ bsum){
  int idx4 = blockIdx.x*256 + threadIdx.x;
  int4 v = make_int4(0,0,0,0);
  if(idx4 < NS/4) v = ((const int4*)cnts)[idx4];
  int s = v.x + v.y + v.z + v.w;
  __shared__ int red[256];
  red[threadIdx.x] = s; __syncthreads();
  for(int d = 128; d > 0; d >>= 1){
    if(threadIdx.x < d) red[threadIdx.x] += red[threadIdx.x + d];
    __syncthreads();
  }
  if(threadIdx.x == 0) bsum[blockIdx.x] = red[0];
}

__global__ __launch_bounds__(64) void k_scanB(int* __restrict__ bsum){
  __shared__ int sb[SCAN_B];
  int t = threadIdx.x;
  if(t < SCAN_B) sb[t] = bsum[t];
  __syncthreads();
  if(t == 0){ int run = 0; for(int i = 0; i < SCAN_B; ++i){ int v = sb[i]; sb[i] = run; run += v; } }
  __syncthreads();
  if(t < SCAN_B) bsum[t] = sb[t];
}

__global__ __launch_bounds__(256) void k_scanC(const int* __restrict__ cnts, const int* __restrict__ bsum,
                                               int* __restrict__ offs, int* __restrict__ pos){
  int t = threadIdx.x;
  int idx4 = blockIdx.x*256 + t;
  int4 v = make_int4(0,0,0,0);
  if(idx4 < NS/4){
    v = ((const int4*)cnts)[idx4];
    ((int4*)pos)[idx4] = make_int4(0,0,0,0);   // zero pos for k_fill
  }
  int s = v.x + v.y + v.z + v.w;
  __shared__ int sc[256];
  sc[t] = s; __syncthreads();
  for(int d = 1; d < 256; d <<= 1){
    int q = (t >= d) ? sc[t-d] : 0; __syncthreads();
    sc[t] += q; __syncthreads();
  }
  int excl = sc[t] - s + bsum[blockIdx.x];
  int base = idx4*4;
  if(base < NS){
    int r = excl;
    offs[base]   = r; r += v.x;
    offs[base+1] = r; r += v.y;
    offs[base+2] = r; r += v.z;
    offs[base+3] = r;
  }
  if(blockIdx.x == SCAN_B-1 && t == 255) offs[NS] = sc[255] + bsum[blockIdx.x];
}

// ---------------------------------------------------------------------------
// Fill CSR buckets (hedge buckets in csrc[0..NEDGE), node buckets after).
// ---------------------------------------------------------------------------
__global__ void k_fill(const int* __restrict__ node_idx, const int* __restrict__ hedge_idx,
                       const int* __restrict__ offs, int* __restrict__ pos,
                       int* __restrict__ csrc){
  int e = blockIdx.x*256 + threadIdx.x;
  if(e < NEDGE){
    int j = hedge_idx[e];
    int n = node_idx[e];
    int p = offs[j] + atomicAdd(&pos[j], 1);
    csrc[p] = n;
    int q = offs[NHEDGE + n] + atomicAdd(&pos[NHEDGE + n], 1);
    csrc[q] = j;
  }
}

// ---------------------------------------------------------------------------
// Phase-1 aggregation from bf16 table -> bf16 aggx + f32 aggw.
// One wave per hedge, lane = 4 cols (ushort4 = 8B). Depth-2 prefetch.
// ---------------------------------------------------------------------------
__global__ __launch_bounds__(256) void k_agg1(const unsigned short* __restrict__ nf_b,
        const float* __restrict__ nrw,
        const int* __restrict__ offs, const int* __restrict__ csrc,
        unsigned short* __restrict__ aggx_b, float* __restrict__ aggw){
  int wv = threadIdx.x >> 6, lane = threadIdx.x & 63;
  int j = blockIdx.x*4 + wv;
  int b = offs[j], cnt = offs[j+1] - b;
  const ushort4* tab = (const ushort4*)nf_b;
  float4 acc = make_float4(0.f,0.f,0.f,0.f);
  float sw = 0.f;
  ushort4 vA = {0,0,0,0}, vB = {0,0,0,0};
  float wA = 0.f, wB = 0.f;
  if(cnt > 0){ int n = csrc[b];   wA = nrw[n]; vA = tab[(size_t)n*64 + lane]; }
  if(cnt > 1){ int n = csrc[b+1]; wB = nrw[n]; vB = tab[(size_t)n*64 + lane]; }
  int k = 0;
  while(k < cnt){
    {
      ushort4 cv = vA; float cw = wA;
      if(k + 2 < cnt){ int n = csrc[b+k+2]; wA = nrw[n]; vA = tab[(size_t)n*64 + lane]; }
      acc.x += cw*bf2f(cv.x); acc.y += cw*bf2f(cv.y);
      acc.z += cw*bf2f(cv.z); acc.w += cw*bf2f(cv.w);
      sw += cw;
    }
    if(++k >= cnt) break;
    {
      ushort4 cv = vB; float cw = wB;
      if(k + 2 < cnt){ int n = csrc[b+k+2]; wB = nrw[n]; vB = tab[(size_t)n*64 + lane]; }
      acc.x += cw*bf2f(cv.x); acc.y += cw*bf2f(cv.y);
      acc.z += cw*bf2f(cv.z); acc.w += cw*bf2f(cv.w);
      sw += cw;
    }
    ++k;
  }
  ushort4 ob;
  ob.x = f2bf(acc.x); ob.y = f2bf(acc.y); ob.z = f2bf(acc.z); ob.w = f2bf(acc.w);
  *(ushort4*)&aggx_b[(size_t)j*HD + lane*4] = ob;
  if(lane == 0) aggw[j] = sw;
}

// ---------------------------------------------------------------------------
// MFMA bf16 GEMM: per wave a 32x64 output tile, operands straight from L2.
// MODE 0: v = prelu((dot + rs_a[r]*cb[c]) / rs_b[r]) -> out_f (f32) + out_b (bf16)
// MODE 1: v = rs_a[r] * (dot + cb[c])               -> out_b (bf16)
// ---------------------------------------------------------------------------
template<int MODE>
__global__ __launch_bounds__(256) void k_gemm(const unsigned short* __restrict__ xb,
        const unsigned short* __restrict__ Wb,
        const float* __restrict__ rs_a, const float* __restrict__ rs_b,
        const float* __restrict__ cb, const float* __restrict__ alpha_p,
        float* __restrict__ out_f, unsigned short* __restrict__ out_b, int M){
  int wv = threadIdx.x >> 6, lane = threadIdx.x & 63;
  int m0 = blockIdx.x*128 + wv*32;
  int n0 = blockIdx.y*64;
  if(m0 >= M) return;
  int lr = lane & 15;
  int lk = (lane >> 4) << 3;
  f32x4 acc[2][4];
  #pragma unroll
  for(int a = 0; a < 2; ++a)
    #pragma unroll
    for(int b = 0; b < 4; ++b) acc[a][b] = (f32x4){0.f,0.f,0.f,0.f};
  const bf16x8 zero8 = {0,0,0,0,0,0,0,0};
  #pragma unroll
  for(int kc = 0; kc < HD; kc += 32){
    bf16x8 af[2], bf[4];
    #pragma unroll
    for(int mi = 0; mi < 2; ++mi){
      int r = m0 + mi*16 + lr;
      af[mi] = (r < M) ? *(const bf16x8*)&xb[(size_t)r*HD + kc + lk] : zero8;
    }
    #pragma unroll
    for(int ni = 0; ni < 4; ++ni){
      int c = n0 + ni*16 + lr;
      bf[ni] = *(const bf16x8*)&Wb[(size_t)c*HD + kc + lk];
    }
    #pragma unroll
    for(int mi = 0; mi < 2; ++mi)
      #pragma unroll
      for(int ni = 0; ni < 4; ++ni)
        acc[mi][ni] = __builtin_amdgcn_mfma_f32_16x16x32_bf16(af[mi], bf[ni], acc[mi][ni], 0, 0, 0);
  }
  float alpha = (MODE == 0) ? *alpha_p : 0.f;
  int rb = (lane >> 4) << 2;
  #pragma unroll
  for(int mi = 0; mi < 2; ++mi){
    #pragma unroll
    for(int j = 0; j < 4; ++j){
      int r = m0 + mi*16 + rb + j;
      if(r < M){
        float ra = rs_a[r];
        float inv = (MODE == 0) ? 1.f / rs_b[r] : 0.f;
        #pragma unroll
        for(int ni = 0; ni < 4; ++ni){
          int c = n0 + ni*16 + lr;
          float d = acc[mi][ni][j];
          if(MODE == 0){
            float v = (d + ra*cb[c]) * inv;
            v = prelu(v, alpha);
            out_f[(size_t)r*HD + c] = v;
            out_b[(size_t)r*HD + c] = f2bf(v);
          } else {
            float v = ra * (d + cb[c]);
            out_b[(size_t)r*HD + c] = f2bf(v);
          }
        }
      }
    }
  }
}

// ---------------------------------------------------------------------------
// Phase-2 aggregation from bf16 y + final epilogue. Depth-2 prefetch.
// ---------------------------------------------------------------------------
__global__ __launch_bounds__(256) void k_agg2(const unsigned short* __restrict__ yb,
        const int* __restrict__ offs, const int* __restrict__ csrc,
        const float* __restrict__ nrs, const float* __restrict__ alpha_p,
        float* __restrict__ out_nodes){
  int wv = threadIdx.x >> 6, lane = threadIdx.x & 63;
  int i = blockIdx.x*4 + wv;
  int b = offs[NHEDGE + i], cnt = offs[NHEDGE + i + 1] - b;
  const ushort4* tab = (const ushort4*)yb;
  float4 acc = make_float4(0.f,0.f,0.f,0.f);
  ushort4 vA = {0,0,0,0}, vB = {0,0,0,0};
  if(cnt > 0){ int j = csrc[b];   vA = tab[(size_t)j*64 + lane]; }
  if(cnt > 1){ int j = csrc[b+1]; vB = tab[(size_t)j*64 + lane]; }
  int k = 0;
  while(k < cnt){
    {
      ushort4 cv = vA;
      if(k + 2 < cnt){ int j = csrc[b+k+2]; vA = tab[(size_t)j*64 + lane]; }
      acc.x += bf2f(cv.x); acc.y += bf2f(cv.y); acc.z += bf2f(cv.z); acc.w += bf2f(cv.w);
    }
    if(++k >= cnt) break;
    {
      ushort4 cv = vB;
      if(k + 2 < cnt){ int j = csrc[b+k+2]; vB = tab[(size_t)j*64 + lane]; }
      acc.x += bf2f(cv.x); acc.y += bf2f(cv.y); acc.z += bf2f(cv.z); acc.w += bf2f(cv.w);
    }
    ++k;
  }
  float inv = 1.f / nrs[i];
  float a = *alpha_p;
  float4 o;
  o.x = prelu(acc.x*inv, a); o.y = prelu(acc.y*inv, a);
  o.z = prelu(acc.z*inv, a); o.w = prelu(acc.w*inv, a);
  *(float4*)&out_nodes[(size_t)i*HD + lane*4] = o;
}

// ---------------------------------------------------------------------------
extern "C" void kernel_launch(void* const* d_in, const int* in_sizes, int n_in,
                              void* d_out, int out_size, void* d_ws, size_t ws_size,
                              hipStream_t stream){
  const float* n_feat   = (const float*)d_in[0];
  const int*   node_idx  = (const int*)d_in[2];
  const int*   hedge_idx = (const int*)d_in[3];
  const float* nrw  = (const float*)d_in[4];
  const float* nrs  = (const float*)d_in[5];
  const float* hrw  = (const float*)d_in[6];
  const float* hrs  = (const float*)d_in[7];
  const float* W_in  = (const float*)d_in[8];
  const float* b_in  = (const float*)d_in[9];
  const float* W_n2e = (const float*)d_in[10];
  const float* b_n2e = (const float*)d_in[11];
  const float* W_e2n = (const float*)d_in[12];
  const float* b_e2n = (const float*)d_in[13];
  const float* alpha = (const float*)d_in[14];

  float* out_nodes = (float*)d_out;
  float* out_efeat = out_nodes + (size_t)NNODE * HD;

  // bf16 n_feat table lives in the out_nodes region of d_out: it is consumed
  // only by k_agg1, and k_agg2 (the last kernel) fully overwrites out_nodes.
  unsigned short* nf_b = (unsigned short*)out_nodes;

  char* p = (char*)d_ws;
  auto take = [&](size_t bytes) -> void* {
    void* r = (void*)p;
    p += (bytes + 255) & ~(size_t)255;
    return r;
  };
  unsigned short* Wb0     = (unsigned short*)take((size_t)HD*HD*2);
  unsigned short* Wb1     = (unsigned short*)take((size_t)HD*HD*2);
  float*          bc      = (float*)take(HD*4);
  float*          aggw    = (float*)take(NHEDGE*4);
  unsigned short* aggx_b  = (unsigned short*)take((size_t)NHEDGE*HD*2);  // aliased as ybuf_b
  unsigned short* efeat_b = (unsigned short*)take((size_t)NHEDGE*HD*2);
  int*            offs    = (int*)take((NS+1)*4);
  int*            cnts    = (int*)take((size_t)NS*4);
  int*            pos     = (int*)take((size_t)NS*4);
  int*            bsum    = (int*)take(SCAN_B*4);
  int*            csrc    = (int*)take((size_t)2*NEDGE*4);
  unsigned short* ybuf_b  = aggx_b;  // safe alias: aggx dead after k_gemm<0>

  hipMemsetAsync(cnts, 0, (size_t)NS*4, stream);

  k_prep<<<HD+1+HIST_B+CVT_B, 256, 0, stream>>>(W_in, b_in, W_n2e, b_n2e, W_e2n,
                                                node_idx, hedge_idx, n_feat,
                                                Wb0, Wb1, bc, cnts, nf_b);
  k_scanA<<<SCAN_B, 256, 0, stream>>>(cnts, bsum);
  k_scanB<<<1, 64, 0, stream>>>(bsum);
  k_scanC<<<SCAN_B, 256, 0, stream>>>(cnts, bsum, offs, pos);
  k_fill<<<(NEDGE+255)/256, 256, 0, stream>>>(node_idx, hedge_idx, offs, pos, csrc);
  k_agg1<<<NHEDGE/4, 256, 0, stream>>>(nf_b, nrw, offs, csrc, aggx_b, aggw);
  k_gemm<0><<<dim3((NHEDGE+127)/128, 4), 256, 0, stream>>>(aggx_b, Wb0, aggw, hrs, bc, alpha,
                                                           out_efeat, efeat_b, NHEDGE);
  k_gemm<1><<<dim3((NHEDGE+127)/128, 4), 256, 0, stream>>>(efeat_b, Wb1, hrw, nullptr, b_e2n, alpha,
                                                           nullptr, ybuf_b, NHEDGE);
  k_agg2<<<NNODE/4, 256, 0, stream>>>(ybuf_b, offs, csrc, nrs, alpha, out_nodes);
}